// Round 2
// baseline (66.521 us; speedup 1.0000x reference)
//
#include <hip/hip_runtime.h>
#include <hip/hip_bf16.h>
#include <stdint.h>

// SVR polynomial-kernel prediction:
//   out[m] = sum_n alpha[n] * (1 + x_p[m].X[n])^4 + b
// m=16384, n=8192, d=64, all fp32 in/out.
// bf16 MFMA (16x16x32, both operands row-major [*,64] = "B^T" layout),
// (1+s)^4*alpha epilogue in-register, fold over n, shuffle-reduce cols.
// R2: NSPLIT 16->32 (8192 waves = 8 waves/SIMD = 100% occupancy) + explicit
// double-buffered B/alpha prefetch to hide L2 latency. Latency-bound fix.

typedef __attribute__((ext_vector_type(8))) short bf16x8;
typedef __attribute__((ext_vector_type(4))) float f32x4;

#define MM 16384
#define NN 8192
#define DD 64
#define NSPLIT 32
#define NC (NN / NSPLIT)   // 256 n per wave
#define MT 4               // 4 m-tiles of 16 rows => 64 rows per wave
#define MROWS 64
#define NTILES (NC / 16)   // 16 iterations

__device__ __forceinline__ unsigned short f2bf(float f) {
    uint32_t u = __float_as_uint(f);
    uint32_t r = (u + 0x7FFFu + ((u >> 16) & 1u)) >> 16;  // round-to-nearest-even
    return (unsigned short)r;
}

__global__ void convert_kernel(const float* __restrict__ xp,
                               const float* __restrict__ X,
                               unsigned short* __restrict__ xbf,
                               unsigned short* __restrict__ Xbf) {
    const int xp4 = MM * DD / 4;          // 262144 float4s
    const int tot4 = xp4 + NN * DD / 4;   // 393216
    int stride = gridDim.x * blockDim.x;
    for (int i = blockIdx.x * blockDim.x + threadIdx.x; i < tot4; i += stride) {
        const float4* src;
        unsigned short* dst;
        int off;
        if (i < xp4) { src = (const float4*)xp; dst = xbf; off = i; }
        else         { src = (const float4*)X;  dst = Xbf; off = i - xp4; }
        float4 v = src[off];
        ushort4 o;
        o.x = f2bf(v.x); o.y = f2bf(v.y); o.z = f2bf(v.z); o.w = f2bf(v.w);
        *(ushort4*)(dst + (size_t)off * 4) = o;
    }
}

__global__ __launch_bounds__(256) void svr_main(
        const unsigned short* __restrict__ xbf,
        const unsigned short* __restrict__ Xbf,
        const float* __restrict__ alpha,
        float* __restrict__ partials) {
    const int lane = threadIdx.x & 63;
    const int gw = (blockIdx.x << 2) + (threadIdx.x >> 6);  // global wave id
    const int mgroup = gw >> 5;            // 0..255  (gw / NSPLIT)
    const int nchunk = gw & (NSPLIT - 1);  // 0..31

    const int r = lane & 15;   // A row within tile / B col within tile
    const int g = lane >> 4;   // k-block selector (k = g*8 + j)

    // Load A fragments for 4 m-tiles (held in registers for whole sweep)
    bf16x8 a[MT][2];
#pragma unroll
    for (int mt = 0; mt < MT; ++mt) {
        const unsigned short* p =
            xbf + (size_t)(mgroup * MROWS + mt * 16 + r) * DD + g * 8;
        a[mt][0] = *(const bf16x8*)p;          // k = 0..31 slice
        a[mt][1] = *(const bf16x8*)(p + 32);   // k = 32..63 slice
    }

    f32x4 red[MT];
#pragma unroll
    for (int mt = 0; mt < MT; ++mt) red[mt] = (f32x4){0.f, 0.f, 0.f, 0.f};

    const int nbase = nchunk * NC;

    // Software-pipelined B/alpha: prefetch tile nt+1 while computing nt.
    const unsigned short* q0 = Xbf + (size_t)(nbase + r) * DD + g * 8;
    bf16x8 b0 = *(const bf16x8*)q0;
    bf16x8 b1 = *(const bf16x8*)(q0 + 32);
    float av = alpha[nbase + r];

#pragma unroll
    for (int nt = 0; nt < NTILES; ++nt) {
        bf16x8 b0n, b1n;
        float avn;
        if (nt + 1 < NTILES) {
            const unsigned short* q =
                Xbf + (size_t)(nbase + (nt + 1) * 16 + r) * DD + g * 8;
            b0n = *(const bf16x8*)q;
            b1n = *(const bf16x8*)(q + 32);
            avn = alpha[nbase + (nt + 1) * 16 + r];
        }
#pragma unroll
        for (int mt = 0; mt < MT; ++mt) {
            f32x4 acc = (f32x4){0.f, 0.f, 0.f, 0.f};
            acc = __builtin_amdgcn_mfma_f32_16x16x32_bf16(a[mt][0], b0, acc, 0, 0, 0);
            acc = __builtin_amdgcn_mfma_f32_16x16x32_bf16(a[mt][1], b1, acc, 0, 0, 0);
            // epilogue: red += alpha[col] * (1 + s)^4
#pragma unroll
            for (int i = 0; i < 4; ++i) {
                float t = 1.0f + acc[i];
                float t2 = t * t;
                red[mt][i] = fmaf(av * t2, t2, red[mt][i]);
            }
        }
        if (nt + 1 < NTILES) { b0 = b0n; b1 = b1n; av = avn; }
    }

    // Reduce across the 16 column-lanes (lane&15); rows live at (g*4+i).
#pragma unroll
    for (int mt = 0; mt < MT; ++mt) {
#pragma unroll
        for (int i = 0; i < 4; ++i) {
            float v = red[mt][i];
            v += __shfl_xor(v, 1);
            v += __shfl_xor(v, 2);
            v += __shfl_xor(v, 4);
            v += __shfl_xor(v, 8);
            red[mt][i] = v;
        }
    }
    if (r == 0) {
#pragma unroll
        for (int mt = 0; mt < MT; ++mt) {
#pragma unroll
            for (int i = 0; i < 4; ++i) {
                int row = mgroup * MROWS + mt * 16 + g * 4 + i;
                partials[(size_t)nchunk * MM + row] = red[mt][i];
            }
        }
    }
}

__global__ void finalize_kernel(const float* __restrict__ partials,
                                const float* __restrict__ bbias,
                                float* __restrict__ out) {
    int m = blockIdx.x * blockDim.x + threadIdx.x;
    if (m < MM) {
        float s = bbias[0];
#pragma unroll
        for (int c = 0; c < NSPLIT; ++c) s += partials[(size_t)c * MM + m];
        out[m] = s;
    }
}

extern "C" void kernel_launch(void* const* d_in, const int* in_sizes, int n_in,
                              void* d_out, int out_size, void* d_ws, size_t ws_size,
                              hipStream_t stream) {
    const float* xp    = (const float*)d_in[0];
    const float* X     = (const float*)d_in[1];
    const float* alpha = (const float*)d_in[2];
    const float* b     = (const float*)d_in[3];
    float* out = (float*)d_out;

    // ws layout: xbf 2MB | Xbf 1MB | partials NSPLIT*MM*4 = 2MB  (total 5MB)
    unsigned short* xbf = (unsigned short*)d_ws;
    unsigned short* Xbf = xbf + (size_t)MM * DD;
    float* partials = (float*)(Xbf + (size_t)NN * DD);

    hipLaunchKernelGGL(convert_kernel, dim3(1024), dim3(256), 0, stream,
                       xp, X, xbf, Xbf);

    const int waves = (MM / MROWS) * NSPLIT;  // 8192 waves
    hipLaunchKernelGGL(svr_main, dim3(waves / 4), dim3(256), 0, stream,
                       xbf, Xbf, alpha, partials);

    hipLaunchKernelGGL(finalize_kernel, dim3(MM / 256), dim3(256), 0, stream,
                       partials, b, out);
}

// Round 3
// 52.328 us; speedup vs baseline: 1.2712x; 1.2712x over previous
//
#include <hip/hip_runtime.h>
#include <hip/hip_bf16.h>
#include <stdint.h>

// SVR polynomial-kernel prediction:
//   out[m] = sum_n alpha[n] * (1 + x_p[m].X[n])^4 + b
// m=16384, n=8192, d=64, all fp32 in/out.
// bf16 MFMA (16x16x32, both operands row-major [*,64] = "B^T" layout),
// (1+s)^4*alpha epilogue in-register, fold over n, shuffle-reduce cols.
// R3: R1 body verbatim (rolled nt loop -> VGPR=40, 8 waves/SIMD possible)
// with NSPLIT=32 only (8192 waves = 32 waves/CU). R2's unroll+prefetch
// blew VGPR to 136 and occupancy to 10% -- do NOT unroll the nt loop.

typedef __attribute__((ext_vector_type(8))) short bf16x8;
typedef __attribute__((ext_vector_type(4))) float f32x4;

#define MM 16384
#define NN 8192
#define DD 64
#define NSPLIT 32
#define NC (NN / NSPLIT)   // 256 n per wave
#define MT 4               // 4 m-tiles of 16 rows => 64 rows per wave
#define MROWS 64

__device__ __forceinline__ unsigned short f2bf(float f) {
    uint32_t u = __float_as_uint(f);
    uint32_t r = (u + 0x7FFFu + ((u >> 16) & 1u)) >> 16;  // round-to-nearest-even
    return (unsigned short)r;
}

__global__ void convert_kernel(const float* __restrict__ xp,
                               const float* __restrict__ X,
                               unsigned short* __restrict__ xbf,
                               unsigned short* __restrict__ Xbf) {
    const int xp4 = MM * DD / 4;          // 262144 float4s
    const int tot4 = xp4 + NN * DD / 4;   // 393216
    int stride = gridDim.x * blockDim.x;
    for (int i = blockIdx.x * blockDim.x + threadIdx.x; i < tot4; i += stride) {
        const float4* src;
        unsigned short* dst;
        int off;
        if (i < xp4) { src = (const float4*)xp; dst = xbf; off = i; }
        else         { src = (const float4*)X;  dst = Xbf; off = i - xp4; }
        float4 v = src[off];
        ushort4 o;
        o.x = f2bf(v.x); o.y = f2bf(v.y); o.z = f2bf(v.z); o.w = f2bf(v.w);
        *(ushort4*)(dst + (size_t)off * 4) = o;
    }
}

__global__ __launch_bounds__(256) void svr_main(
        const unsigned short* __restrict__ xbf,
        const unsigned short* __restrict__ Xbf,
        const float* __restrict__ alpha,
        float* __restrict__ partials) {
    const int lane = threadIdx.x & 63;
    const int gw = (blockIdx.x << 2) + (threadIdx.x >> 6);  // global wave id
    const int mgroup = gw >> 5;            // 0..255  (gw / NSPLIT)
    const int nchunk = gw & (NSPLIT - 1);  // 0..31

    const int r = lane & 15;   // A row within tile / B col within tile
    const int g = lane >> 4;   // k-block selector (k = g*8 + j)

    // Load A fragments for 4 m-tiles (held in registers for whole sweep)
    bf16x8 a[MT][2];
#pragma unroll
    for (int mt = 0; mt < MT; ++mt) {
        const unsigned short* p =
            xbf + (size_t)(mgroup * MROWS + mt * 16 + r) * DD + g * 8;
        a[mt][0] = *(const bf16x8*)p;          // k = 0..31 slice
        a[mt][1] = *(const bf16x8*)(p + 32);   // k = 32..63 slice
    }

    f32x4 red[MT];
#pragma unroll
    for (int mt = 0; mt < MT; ++mt) red[mt] = (f32x4){0.f, 0.f, 0.f, 0.f};

    const int nbase = nchunk * NC;
    for (int nt = 0; nt < NC / 16; ++nt) {
        const int n0 = nbase + nt * 16;
        const unsigned short* q = Xbf + (size_t)(n0 + r) * DD + g * 8;
        bf16x8 b0 = *(const bf16x8*)q;
        bf16x8 b1 = *(const bf16x8*)(q + 32);
        float av = alpha[n0 + r];  // alpha for this lane's output column
#pragma unroll
        for (int mt = 0; mt < MT; ++mt) {
            f32x4 acc = (f32x4){0.f, 0.f, 0.f, 0.f};
            acc = __builtin_amdgcn_mfma_f32_16x16x32_bf16(a[mt][0], b0, acc, 0, 0, 0);
            acc = __builtin_amdgcn_mfma_f32_16x16x32_bf16(a[mt][1], b1, acc, 0, 0, 0);
            // epilogue: red += alpha[col] * (1 + s)^4
#pragma unroll
            for (int i = 0; i < 4; ++i) {
                float t = 1.0f + acc[i];
                float t2 = t * t;
                float t4 = t2 * t2;
                red[mt][i] = fmaf(av, t4, red[mt][i]);
            }
        }
    }

    // Reduce across the 16 column-lanes (lane&15); rows live at (g*4+i).
#pragma unroll
    for (int mt = 0; mt < MT; ++mt) {
#pragma unroll
        for (int i = 0; i < 4; ++i) {
            float v = red[mt][i];
            v += __shfl_xor(v, 1);
            v += __shfl_xor(v, 2);
            v += __shfl_xor(v, 4);
            v += __shfl_xor(v, 8);
            red[mt][i] = v;
        }
    }
    if (r == 0) {
#pragma unroll
        for (int mt = 0; mt < MT; ++mt) {
#pragma unroll
            for (int i = 0; i < 4; ++i) {
                int row = mgroup * MROWS + mt * 16 + g * 4 + i;
                partials[(size_t)nchunk * MM + row] = red[mt][i];
            }
        }
    }
}

__global__ void finalize_kernel(const float* __restrict__ partials,
                                const float* __restrict__ bbias,
                                float* __restrict__ out) {
    int m = blockIdx.x * blockDim.x + threadIdx.x;
    if (m < MM) {
        float s = bbias[0];
#pragma unroll
        for (int c = 0; c < NSPLIT; ++c) s += partials[(size_t)c * MM + m];
        out[m] = s;
    }
}

extern "C" void kernel_launch(void* const* d_in, const int* in_sizes, int n_in,
                              void* d_out, int out_size, void* d_ws, size_t ws_size,
                              hipStream_t stream) {
    const float* xp    = (const float*)d_in[0];
    const float* X     = (const float*)d_in[1];
    const float* alpha = (const float*)d_in[2];
    const float* b     = (const float*)d_in[3];
    float* out = (float*)d_out;

    // ws layout: xbf 2MB | Xbf 1MB | partials NSPLIT*MM*4 = 2MB  (total 5MB)
    unsigned short* xbf = (unsigned short*)d_ws;
    unsigned short* Xbf = xbf + (size_t)MM * DD;
    float* partials = (float*)(Xbf + (size_t)NN * DD);

    hipLaunchKernelGGL(convert_kernel, dim3(1024), dim3(256), 0, stream,
                       xp, X, xbf, Xbf);

    const int waves = (MM / MROWS) * NSPLIT;  // 8192 waves
    hipLaunchKernelGGL(svr_main, dim3(waves / 4), dim3(256), 0, stream,
                       xbf, Xbf, alpha, partials);

    hipLaunchKernelGGL(finalize_kernel, dim3(MM / 256), dim3(256), 0, stream,
                       partials, b, out);
}

// Round 4
// 41.500 us; speedup vs baseline: 1.6029x; 1.2609x over previous
//
#include <hip/hip_runtime.h>
#include <hip/hip_bf16.h>
#include <stdint.h>

// SVR polynomial-kernel prediction:
//   out[m] = sum_n alpha[n] * (1 + x_p[m].X[n])^4 + b
// m=16384, n=8192, d=64, all fp32 in/out.
// bf16 MFMA 16x16x32, both operands row-major [*,64] ("B^T" layout).
// R4: MT=8 (128 m-rows/wave -> halve L2 X-traffic, 16 MFMA/iter covers L2
//     latency), alpha folded into X (X prescaled by alpha^(1/4); epilogue
//     t=a4+s, t2=t*t, red=fma(t2,t2,red) -> 3 VALU/elem), rolled 2-stage
//     prefetch with "#pragma unroll 1" (R2 lesson: unrolling nt -> VGPR 136).

typedef __attribute__((ext_vector_type(8))) short bf16x8;
typedef __attribute__((ext_vector_type(4))) float f32x4;

#define MM 16384
#define NN 8192
#define DD 64
#define NSPLIT 32
#define NC (NN / NSPLIT)   // 256 n per wave
#define MT 8               // 8 m-tiles of 16 rows => 128 rows per wave
#define MROWS 128
#define NTILES (NC / 16)   // 16 iterations

__device__ __forceinline__ unsigned short f2bf(float f) {
    uint32_t u = __float_as_uint(f);
    uint32_t r = (u + 0x7FFFu + ((u >> 16) & 1u)) >> 16;  // round-to-nearest-even
    return (unsigned short)r;
}

// xp -> bf16; X -> bf16 prescaled by alpha[n]^(1/4); alpha4f[n] = alpha[n]^(1/4)
__global__ void convert_kernel(const float* __restrict__ xp,
                               const float* __restrict__ X,
                               const float* __restrict__ alpha,
                               unsigned short* __restrict__ xbf,
                               unsigned short* __restrict__ Xbf,
                               float* __restrict__ alpha4f) {
    const int xp4 = MM * DD / 4;          // 262144 float4s
    const int X4 = NN * DD / 4;           // 131072 float4s
    const int tot4 = xp4 + X4;
    int tid0 = blockIdx.x * blockDim.x + threadIdx.x;
    int stride = gridDim.x * blockDim.x;
    for (int i = tid0; i < tot4; i += stride) {
        if (i < xp4) {
            float4 v = ((const float4*)xp)[i];
            ushort4 o;
            o.x = f2bf(v.x); o.y = f2bf(v.y); o.z = f2bf(v.z); o.w = f2bf(v.w);
            *(ushort4*)(xbf + (size_t)i * 4) = o;
        } else {
            int off = i - xp4;
            int row = off >> 4;           // 16 float4 per 64-elem row
            float a4 = sqrtf(sqrtf(alpha[row]));
            float4 v = ((const float4*)X)[off];
            ushort4 o;
            o.x = f2bf(v.x * a4); o.y = f2bf(v.y * a4);
            o.z = f2bf(v.z * a4); o.w = f2bf(v.w * a4);
            *(ushort4*)(Xbf + (size_t)off * 4) = o;
        }
    }
    if (tid0 < NN) alpha4f[tid0] = sqrtf(sqrtf(alpha[tid0]));
}

__global__ __launch_bounds__(256) void svr_main(
        const unsigned short* __restrict__ xbf,
        const unsigned short* __restrict__ Xbf,
        const float* __restrict__ alpha4f,
        float* __restrict__ partials) {
    const int lane = threadIdx.x & 63;
    const int gw = (blockIdx.x << 2) + (threadIdx.x >> 6);  // global wave id
    const int mgroup = gw >> 5;            // 0..127  (gw / NSPLIT)
    const int nchunk = gw & (NSPLIT - 1);  // 0..31

    const int r = lane & 15;   // A row within tile / B col within tile
    const int g = lane >> 4;   // k-block selector (k = g*8 + j)

    // Load A fragments for 8 m-tiles (held in registers for whole sweep)
    bf16x8 a[MT][2];
#pragma unroll
    for (int mt = 0; mt < MT; ++mt) {
        const unsigned short* p =
            xbf + (size_t)(mgroup * MROWS + mt * 16 + r) * DD + g * 8;
        a[mt][0] = *(const bf16x8*)p;          // k = 0..31 slice
        a[mt][1] = *(const bf16x8*)(p + 32);   // k = 32..63 slice
    }

    f32x4 red[MT];
#pragma unroll
    for (int mt = 0; mt < MT; ++mt) red[mt] = (f32x4){0.f, 0.f, 0.f, 0.f};

    const int nbase = nchunk * NC;

    // 2-stage pipeline, rolled loop (do NOT unroll: VGPR blowup, see R2)
    const unsigned short* q0 = Xbf + (size_t)(nbase + r) * DD + g * 8;
    bf16x8 b0 = *(const bf16x8*)q0;
    bf16x8 b1 = *(const bf16x8*)(q0 + 32);
    float av4 = alpha4f[nbase + r];

#pragma unroll 1
    for (int nt = 0; nt < NTILES; ++nt) {
        bf16x8 b0n, b1n;
        float av4n;
        if (nt + 1 < NTILES) {
            const unsigned short* q =
                Xbf + (size_t)(nbase + (nt + 1) * 16 + r) * DD + g * 8;
            b0n = *(const bf16x8*)q;
            b1n = *(const bf16x8*)(q + 32);
            av4n = alpha4f[nbase + (nt + 1) * 16 + r];
        }
#pragma unroll
        for (int mt = 0; mt < MT; ++mt) {
            f32x4 acc = (f32x4){0.f, 0.f, 0.f, 0.f};
            acc = __builtin_amdgcn_mfma_f32_16x16x32_bf16(a[mt][0], b0, acc, 0, 0, 0);
            acc = __builtin_amdgcn_mfma_f32_16x16x32_bf16(a[mt][1], b1, acc, 0, 0, 0);
            // epilogue: red += (a4 + s)^4  where s = a4 * (x.X)
#pragma unroll
            for (int i = 0; i < 4; ++i) {
                float t = av4 + acc[i];
                float t2 = t * t;
                red[mt][i] = fmaf(t2, t2, red[mt][i]);
            }
        }
        if (nt + 1 < NTILES) { b0 = b0n; b1 = b1n; av4 = av4n; }
    }

    // Reduce across the 16 column-lanes (lane&15); rows live at (g*4+i).
#pragma unroll
    for (int mt = 0; mt < MT; ++mt) {
#pragma unroll
        for (int i = 0; i < 4; ++i) {
            float v = red[mt][i];
            v += __shfl_xor(v, 1);
            v += __shfl_xor(v, 2);
            v += __shfl_xor(v, 4);
            v += __shfl_xor(v, 8);
            red[mt][i] = v;
        }
    }
    if (r == 0) {
#pragma unroll
        for (int mt = 0; mt < MT; ++mt) {
#pragma unroll
            for (int i = 0; i < 4; ++i) {
                int row = mgroup * MROWS + mt * 16 + g * 4 + i;
                partials[(size_t)nchunk * MM + row] = red[mt][i];
            }
        }
    }
}

__global__ void finalize_kernel(const float* __restrict__ partials,
                                const float* __restrict__ bbias,
                                float* __restrict__ out) {
    int m = blockIdx.x * blockDim.x + threadIdx.x;
    if (m < MM) {
        float s = bbias[0];
#pragma unroll
        for (int c = 0; c < NSPLIT; ++c) s += partials[(size_t)c * MM + m];
        out[m] = s;
    }
}

extern "C" void kernel_launch(void* const* d_in, const int* in_sizes, int n_in,
                              void* d_out, int out_size, void* d_ws, size_t ws_size,
                              hipStream_t stream) {
    const float* xp    = (const float*)d_in[0];
    const float* X     = (const float*)d_in[1];
    const float* alpha = (const float*)d_in[2];
    const float* b     = (const float*)d_in[3];
    float* out = (float*)d_out;

    // ws layout: xbf 2MB | Xbf 1MB | alpha4f 32KB | partials 32*16384*4 = 2MB
    unsigned short* xbf = (unsigned short*)d_ws;
    unsigned short* Xbf = xbf + (size_t)MM * DD;
    float* alpha4f = (float*)(Xbf + (size_t)NN * DD);
    float* partials = alpha4f + NN;

    hipLaunchKernelGGL(convert_kernel, dim3(1024), dim3(256), 0, stream,
                       xp, X, alpha, xbf, Xbf, alpha4f);

    const int waves = (MM / MROWS) * NSPLIT;  // 4096 waves
    hipLaunchKernelGGL(svr_main, dim3(waves / 4), dim3(256), 0, stream,
                       xbf, Xbf, alpha4f, partials);

    hipLaunchKernelGGL(finalize_kernel, dim3(MM / 256), dim3(256), 0, stream,
                       partials, b, out);
}